// Round 1
// baseline (297.226 us; speedup 1.0000x reference)
//
#include <hip/hip_runtime.h>

// Fused RK4 step for 2D Burgers-like PDE, periodic BCs, radius-2 stencils.
// One kernel: tile 64x64 output, 80x80 staged (halo 8 = 4 stages x radius 2).
// Stage inputs live in LDS (in-place ping via regs + barriers); u0/v0/acc in regs.

typedef float f4 __attribute__((ext_vector_type(4)));

#define LCOLS 88            // 4 pad + 80 + 4 pad
#define LROWS 84            // 2 pad + 80 + 2 pad
#define NBUF  (LROWS*LCOLS) // 7392 floats = 29568 B per field buffer
#define NQ    7             // max owned quads per thread (1600 quads / 256 thr)

__global__ __launch_bounds__(256, 2)
void rk4_stencil(const float* __restrict__ h,
                 const float* __restrict__ sRe, const float* __restrict__ sUA,
                 const float* __restrict__ sUB, const float* __restrict__ sVA,
                 const float* __restrict__ sVB, float* __restrict__ out)
{
    __shared__ __align__(16) float tu[NBUF];
    __shared__ __align__(16) float tv[NBUF];

    const int tid = threadIdx.x;
    const int tc = blockIdx.x, tr = blockIdx.y, bb = blockIdx.z;

    const float Re = sRe[0], UA = sUA[0], UB = sUB[0], VA = sVA[0], VB = sVB[0];
    const float nu = 0.001f / Re;

    // stencil coeffs (already divided by DX / DX^2, DX=0.01)
    const float d1 = 800.f/12.f;          // (8/12)/DX
    const float d2 = 100.f/12.f;          // (1/12)/DX
    const float a1 = (4.f/3.f)*1.0e4f;    // (4/3)/DX^2
    const float a2 = -(1.f/12.f)*1.0e4f;  // (-1/12)/DX^2
    const float a0 = -5.0e4f;             // -5/DX^2 (both axes combined center)

    // zero LDS (pads must be finite; interior overwritten by load)
    for (int i = tid; i < NBUF; i += 256) { tu[i] = 0.f; tv[i] = 0.f; }
    __syncthreads();

    const size_t plane = 1048576;
    const float* uin = h + (size_t)(bb*2) * plane;
    const float* vin = uin + plane;
    const int base_r = tr*64 - 8, base_c = tc*64 - 8;

    // stage 80x80 u0,v0 into LDS (wrap indexing), coalesced along columns
    for (int i = tid; i < 6400; i += 256) {
        int r = i / 80;
        int c = i - r*80;
        int gr = (base_r + r) & 1023;
        int gc = (base_c + c) & 1023;
        int l = (r+2)*LCOLS + 4 + c;
        tu[l] = uin[gr*1024 + gc];
        tv[l] = vin[gr*1024 + gc];
    }
    __syncthreads();

    // ownership: quad q = tid + 256*j ; quad (qr, qc): row qr in [0,80), col cells 4*qc..4*qc+3
    int  lidx[NQ]; bool has[NQ]; int qrA[NQ], qcA[NQ];
    f4 u0[NQ], v0[NQ], au[NQ], av[NQ];
    const f4 z4 = {0.f, 0.f, 0.f, 0.f};
#pragma unroll
    for (int j = 0; j < NQ; ++j) {
        int q = tid + 256*j;
        has[j] = (q < 1600);
        int qr = q / 20, qc = q - qr*20;
        qrA[j] = qr; qcA[j] = qc;
        lidx[j] = (qr+2)*LCOLS + 4 + 4*qc;
        au[j] = z4; av[j] = z4;
        if (has[j]) {
            u0[j] = *(const f4*)(tu + lidx[j]);
            v0[j] = *(const f4*)(tv + lidx[j]);
        }
    }

    const float cs0 = 0.25f, cs1 = 0.25f, cs2 = 0.5f; // DT/2, DT/2, DT
#pragma unroll
    for (int s = 0; s < 4; ++s) {
        const float wgt = (s == 1 || s == 2) ? 2.f : 1.f;
        const float csc = (s == 0) ? cs0 : (s == 1) ? cs1 : cs2;
        f4 stu[NQ], stv[NQ];
#pragma unroll
        for (int j = 0; j < NQ; ++j) {
            if (!has[j]) continue;
            const int l = lidx[j];
            f4 ucc = *(const f4*)(tu+l);
            f4 ucl = *(const f4*)(tu+l-4);
            f4 ucr = *(const f4*)(tu+l+4);
            f4 un1 = *(const f4*)(tu+l-LCOLS);
            f4 us1 = *(const f4*)(tu+l+LCOLS);
            f4 un2 = *(const f4*)(tu+l-2*LCOLS);
            f4 us2 = *(const f4*)(tu+l+2*LCOLS);
            f4 vcc = *(const f4*)(tv+l);
            f4 vcl = *(const f4*)(tv+l-4);
            f4 vcr = *(const f4*)(tv+l+4);
            f4 vn1 = *(const f4*)(tv+l-LCOLS);
            f4 vs1 = *(const f4*)(tv+l+LCOLS);
            f4 vn2 = *(const f4*)(tv+l-2*LCOLS);
            f4 vs2 = *(const f4*)(tv+l+2*LCOLS);
            float hu[8] = {ucl[2],ucl[3],ucc[0],ucc[1],ucc[2],ucc[3],ucr[0],ucr[1]};
            float hv[8] = {vcl[2],vcl[3],vcc[0],vcc[1],vcc[2],vcc[3],vcr[0],vcr[1]};
#pragma unroll
            for (int k = 0; k < 4; ++k) {
                float u = hu[k+2], v = hv[k+2];
                // derivative along rows (axis 2) = reference's u_x (K_DX)
                float urow = d1*(us1[k]-un1[k]) + d2*(un2[k]-us2[k]);
                float vrow = d1*(vs1[k]-vn1[k]) + d2*(vn2[k]-vs2[k]);
                // derivative along cols (axis 3) = reference's u_y (K_DY)
                float ucol = d1*(hu[k+3]-hu[k+1]) + d2*(hu[k]-hu[k+4]);
                float vcol = d1*(hv[k+3]-hv[k+1]) + d2*(hv[k]-hv[k+4]);
                float ulap = a1*((un1[k]+us1[k])+(hu[k+1]+hu[k+3]))
                           + a2*((un2[k]+us2[k])+(hu[k]+hu[k+4])) + a0*u;
                float vlap = a1*((vn1[k]+vs1[k])+(hv[k+1]+hv[k+3]))
                           + a2*((vn2[k]+vs2[k])+(hv[k]+hv[k+4])) + a0*v;
                float fu = nu*ulap + UA*(u*urow) + UB*(v*ucol);
                float fv = nu*vlap + VA*(u*vrow) + VB*(v*vcol);
                au[j][k] += wgt*fu;
                av[j][k] += wgt*fv;
                if (s < 3) {
                    stu[j][k] = u0[j][k] + csc*fu;
                    stv[j][k] = v0[j][k] + csc*fv;
                }
            }
        }
        if (s < 3) {
            __syncthreads();   // all reads of t_s done
#pragma unroll
            for (int j = 0; j < NQ; ++j) {
                if (!has[j]) continue;
                *(f4*)(tu+lidx[j]) = stu[j];
                *(f4*)(tv+lidx[j]) = stv[j];
            }
            __syncthreads();   // t_{s+1} visible
        }
    }

    // epilogue: out = u0 + (DT/6) * (k1 + 2k2 + 2k3 + k4); interior cells [8,72)^2
    float* outu = out + (size_t)(bb*2) * plane;
    float* outv = outu + plane;
#pragma unroll
    for (int j = 0; j < NQ; ++j) {
        if (!has[j]) continue;
        int qr = qrA[j], qc = qcA[j];
        if (qr >= 8 && qr < 72 && qc >= 2 && qc < 18) {
            int gr = tr*64 + qr - 8;
            int gc = tc*64 + 4*qc - 8;
            f4 ru, rv;
#pragma unroll
            for (int k = 0; k < 4; ++k) {
                ru[k] = u0[j][k] + (1.f/12.f)*au[j][k];
                rv[k] = v0[j][k] + (1.f/12.f)*av[j][k];
            }
            *(f4*)(outu + (size_t)gr*1024 + gc) = ru;
            *(f4*)(outv + (size_t)gr*1024 + gc) = rv;
        }
    }
}

extern "C" void kernel_launch(void* const* d_in, const int* in_sizes, int n_in,
                              void* d_out, int out_size, void* d_ws, size_t ws_size,
                              hipStream_t stream) {
    const float* h   = (const float*)d_in[0];
    const float* sRe = (const float*)d_in[1];
    const float* sUA = (const float*)d_in[2];
    const float* sUB = (const float*)d_in[3];
    const float* sVA = (const float*)d_in[4];
    const float* sVB = (const float*)d_in[5];
    float* o = (float*)d_out;
    rk4_stencil<<<dim3(16,16,8), dim3(256,1,1), 0, stream>>>(h, sRe, sUA, sUB, sVA, sVB, o);
}